// Round 8
// baseline (358.822 us; speedup 1.0000x reference)
//
#include <hip/hip_runtime.h>

typedef unsigned short u16;
typedef unsigned int u32;
typedef __attribute__((ext_vector_type(4))) float f32x4;
typedef __attribute__((ext_vector_type(4))) u16 u16x4;
typedef __attribute__((ext_vector_type(8))) u16 u16x8;
typedef __attribute__((ext_vector_type(8))) __bf16 bf16x8;

#define DEV static __device__ __forceinline__

DEV u16 f2b(float f) {
  u32 u = __builtin_bit_cast(u32, f);
  u32 r = (u + 0x7fffu + ((u >> 16) & 1u)) >> 16;
  return (u16)r;
}

DEV bf16x8 mk8(u16x4 lo, u16x4 hi) {
  u16x8 v = __builtin_shufflevector(lo, hi, 0, 1, 2, 3, 4, 5, 6, 7);
  return __builtin_bit_cast(bf16x8, v);
}

// ---------------------------------------------------------------------------
// Stage 0: convert X (key/value/query, each [128,512] f32) -> bf16 row-major.
// ---------------------------------------------------------------------------
__global__ __launch_bounds__(256) void prep_x(
    const float* __restrict__ key, const float* __restrict__ value,
    const float* __restrict__ query, u16* __restrict__ Xb)
{
  int idx = blockIdx.x * 256 + threadIdx.x;      // 0..49151
  int mat = idx >> 14;
  int off = (idx & 16383) * 4;
  const float* src = mat == 0 ? key : (mat == 1 ? value : query);
  f32x4 v = *(const f32x4*)(src + off);
  u16x4 o;
#pragma unroll
  for (int i = 0; i < 4; ++i) o[i] = __builtin_bit_cast(u16, (__bf16)v[i]);
  *(u16x4*)(Xb + mat * 65536 + off) = o;
}

// ---------------------------------------------------------------------------
// Stage 1: QKV projection.  Xb[mat][128,512]bf16 @ W[512,65536]f32 + b -> bf16.
// grid 1536, block 256 (4 waves, 2x2, 64x64 out each).  BM=128, BN=128, BK=32.
// B reg-staged f32 -> converted -> bf16 LDS (8 KB dbuf); A via LDS-DMA.
// Total LDS 32 KB -> 5 blocks/CU (20 waves/CU).  Bank rotations:
// B physical col = (n + (k>>3)*16) & 127; A sigma(m)=(m>>1)&3 chunk rotation.
// LDS layout within smem[16384] u16:
//   Bs buf c: smem + c*4096   ([32][128] bf16)
//   As buf c: smem + 8192 + c*4096  ([128][32] bf16)
// Epilogue reuses smem as [128][128] bf16 C tile -> 256 B contiguous stores.
// ---------------------------------------------------------------------------
__global__ __launch_bounds__(256, 5) void qkv_gemm(
    const u16* __restrict__ Xb,
    const float* __restrict__ Wk, const float* __restrict__ bk,
    const float* __restrict__ Wv, const float* __restrict__ bv,
    const float* __restrict__ Wq, const float* __restrict__ bq,
    u16* __restrict__ Kp, u16* __restrict__ Vp, u16* __restrict__ Qp)
{
  const int bx = blockIdx.x;
  const int mat = bx >> 9;
  const float* W    = mat == 0 ? Wk : (mat == 1 ? Wv : Wq);
  const float* bias = mat == 0 ? bk : (mat == 1 ? bv : bq);
  u16* out          = mat == 0 ? Kp : (mat == 1 ? Vp : Qp);
  const u16* Xm = Xb + mat * 65536;
  const int n0 = (bx & 511) * 128;

  __shared__ u16 smem[16384];                // 32 KB total

  const int t0 = threadIdx.x, lane = t0 & 63, wv = t0 >> 6;
  const int wm = wv >> 1, wn = wv & 1;
  const int l15 = lane & 15, lg = lane >> 4;

  const int brow = wv * 8 + (lane >> 5);     // +2p: B row this lane stages
  const int bcol = (lane & 31) * 4;          // B col this lane stages

  f32x4 acc[4][4];
#pragma unroll
  for (int i = 0; i < 4; ++i)
#pragma unroll
    for (int j = 0; j < 4; ++j) acc[i][j] = (f32x4){0.f, 0.f, 0.f, 0.f};

  // ---- prologue: stage tile 0 into buffer 0 ----
  {
    f32x4 rB[4];
#pragma unroll
    for (int p = 0; p < 4; ++p) {
      int row = brow + p * 2;
      rB[p] = *(const f32x4*)(W + (size_t)row * 65536 + n0 + bcol);
    }
#pragma unroll
    for (int p = 0; p < 2; ++p) {
      int q = wv * 2 + p;
      int m = q * 16 + (lane >> 2);
      int sc = ((lane & 3) - ((m >> 1) & 3)) & 3;
      const u16* gp = Xm + m * 512 + sc * 8;
      u16* lp = smem + 8192 + q * 512;
      __builtin_amdgcn_global_load_lds(
          (const __attribute__((address_space(1))) u32*)gp,
          (__attribute__((address_space(3))) u32*)lp, 16, 0, 0);
    }
#pragma unroll
    for (int p = 0; p < 4; ++p) {
      int row = brow + p * 2;
      int pc = (bcol + ((row >> 3) << 4)) & 127;
      u16x4 cv;
#pragma unroll
      for (int i = 0; i < 4; ++i) cv[i] = __builtin_bit_cast(u16, (__bf16)rB[p][i]);
      *(u16x4*)&smem[row * 128 + pc] = cv;
    }
    __syncthreads();
  }

  for (int t = 0; t < 16; ++t) {
    const int cur = (t & 1) * 4096, nxt = cur ^ 4096;
    f32x4 rB[4];
    // region 1: issue next-tile loads (covered by compute below)
    if (t < 15) {
      const int k0n = (t + 1) * 32;
#pragma unroll
      for (int p = 0; p < 4; ++p) {
        int row = brow + p * 2;
        rB[p] = *(const f32x4*)(W + (size_t)(k0n + row) * 65536 + n0 + bcol);
      }
#pragma unroll
      for (int p = 0; p < 2; ++p) {
        int q = wv * 2 + p;
        int m = q * 16 + (lane >> 2);
        int sc = ((lane & 3) - ((m >> 1) & 3)) & 3;
        const u16* gp = Xm + m * 512 + k0n + sc * 8;
        u16* lp = smem + 8192 + nxt + q * 512;
        __builtin_amdgcn_global_load_lds(
            (const __attribute__((address_space(1))) u32*)gp,
            (__attribute__((address_space(3))) u32*)lp, 16, 0, 0);
      }
    }
    __builtin_amdgcn_sched_barrier(0);
    // region 2: compute tile t
    {
      bf16x8 af[4];
#pragma unroll
      for (int mf = 0; mf < 4; ++mf) {
        int m = wm * 64 + mf * 16 + l15;
        af[mf] = *(const bf16x8*)&smem[8192 + cur + m * 32 + ((lg + ((m >> 1) & 3)) & 3) * 8];
      }
#pragma unroll
      for (int nf = 0; nf < 4; ++nf) {
        int pc = (wn * 64 + nf * 16 + l15 + lg * 16) & 127;
        u16x8 bw;
#pragma unroll
        for (int j = 0; j < 8; ++j) bw[j] = smem[cur + (lg * 8 + j) * 128 + pc];
        bf16x8 bv = __builtin_bit_cast(bf16x8, bw);
#pragma unroll
        for (int mf = 0; mf < 4; ++mf)
          acc[mf][nf] = __builtin_amdgcn_mfma_f32_16x16x32_bf16(af[mf], bv, acc[mf][nf], 0, 0, 0);
      }
    }
    __builtin_amdgcn_sched_barrier(0);
    // region 3: convert + commit staged B to the other buffer
    if (t < 15) {
#pragma unroll
      for (int p = 0; p < 4; ++p) {
        int row = brow + p * 2;
        int pc = (bcol + ((row >> 3) << 4)) & 127;
        u16x4 cv;
#pragma unroll
        for (int i = 0; i < 4; ++i) cv[i] = __builtin_bit_cast(u16, (__bf16)rB[p][i]);
        *(u16x4*)&smem[nxt + row * 128 + pc] = cv;
      }
    }
    __syncthreads();
  }

  // ---- epilogue: acc + bias -> LDS bf16 tile -> coalesced stores ----
#pragma unroll
  for (int nf = 0; nf < 4; ++nf) {
    int col = wn * 64 + nf * 16 + l15;
    float bv_ = bias[n0 + col];
#pragma unroll
    for (int mf = 0; mf < 4; ++mf) {
      int row0 = wm * 64 + mf * 16 + lg * 4;
#pragma unroll
      for (int r = 0; r < 4; ++r)
        smem[(row0 + r) * 128 + col] = f2b(acc[mf][nf][r] + bv_);
    }
  }
  __syncthreads();
#pragma unroll
  for (int rr = 0; rr < 16; ++rr) {
    int row = wv * 32 + rr * 2 + (lane >> 5);
    int c = (lane & 31) * 4;
    u16x4 v = *(const u16x4*)&smem[row * 128 + c];
    *(u16x4*)(out + (size_t)row * 65536 + n0 + c) = v;
  }
}

// ---------------------------------------------------------------------------
// Stage 2: attention per (b,h) (UNCHANGED).
// ---------------------------------------------------------------------------
__global__ __launch_bounds__(256) void attn_kernel(
    const u16* __restrict__ Qp, const u16* __restrict__ Kp, const u16* __restrict__ Vp,
    float* __restrict__ attnOut, u16* __restrict__ ctx)
{
  const int bh = blockIdx.x;
  const int b = bh >> 4, h = bh & 15;
  const size_t base = (size_t)b * 65536 + h * 4096;

  __shared__ u16 qS[8 * 512];
  __shared__ u16 kS[8 * 512];
  __shared__ u16 vS[32 * 128];
  __shared__ u16 pS[32 * 512];

  const int t = threadIdx.x;
  const int lane = t & 63, w = t >> 6;
  const int l15 = lane & 15, lg = lane >> 4;

#pragma unroll
  for (int p = 0; p < 2; ++p) {
    int idx = p * 256 + t;
    int s = idx >> 2, dc = idx & 3;
    u16x8 qv = *(const u16x8*)(Qp + base + s * 32 + dc * 8);
    u16x8 kv = *(const u16x8*)(Kp + base + s * 32 + dc * 8);
    u16x8 vv = *(const u16x8*)(Vp + base + s * 32 + dc * 8);
    *(u16x4*)(qS + (dc * 2) * 512 + s * 4)     = __builtin_shufflevector(qv, qv, 0, 1, 2, 3);
    *(u16x4*)(qS + (dc * 2 + 1) * 512 + s * 4) = __builtin_shufflevector(qv, qv, 4, 5, 6, 7);
    *(u16x4*)(kS + (dc * 2) * 512 + s * 4)     = __builtin_shufflevector(kv, kv, 0, 1, 2, 3);
    *(u16x4*)(kS + (dc * 2 + 1) * 512 + s * 4) = __builtin_shufflevector(kv, kv, 4, 5, 6, 7);
#pragma unroll
    for (int i = 0; i < 8; ++i)
      vS[(s >> 2) * 128 + (dc * 8 + i) * 4 + (s & 3)] = vv[i];
  }
  __syncthreads();

  f32x4 sc[2][8];
#pragma unroll
  for (int i = 0; i < 2; ++i)
#pragma unroll
    for (int j = 0; j < 8; ++j) sc[i][j] = (f32x4){0.f, 0.f, 0.f, 0.f};

  {
    const int kqA = lg * 2;
    bf16x8 aq[2];
#pragma unroll
    for (int mf = 0; mf < 2; ++mf) {
      int m = w * 32 + mf * 16 + l15;
      u16x4 lo = *(const u16x4*)(qS + kqA * 512 + m * 4);
      u16x4 hi = *(const u16x4*)(qS + (kqA + 1) * 512 + m * 4);
      aq[mf] = mk8(lo, hi);
    }
#pragma unroll
    for (int nf = 0; nf < 8; ++nf) {
      int j = nf * 16 + l15;
      u16x4 lo = *(const u16x4*)(kS + kqA * 512 + j * 4);
      u16x4 hi = *(const u16x4*)(kS + (kqA + 1) * 512 + j * 4);
      bf16x8 bk8 = mk8(lo, hi);
#pragma unroll
      for (int mf = 0; mf < 2; ++mf)
        sc[mf][nf] = __builtin_amdgcn_mfma_f32_16x16x32_bf16(aq[mf], bk8, sc[mf][nf], 0, 0, 0);
    }
  }

  const float SCL = 0.70710678118654752f;
#pragma unroll
  for (int mf = 0; mf < 2; ++mf) {
#pragma unroll
    for (int r = 0; r < 4; ++r) {
      float m8 = -1e30f;
#pragma unroll
      for (int nf = 0; nf < 8; ++nf) m8 = fmaxf(m8, sc[mf][nf][r]);
      m8 = fmaxf(m8, __shfl_xor(m8, 1));
      m8 = fmaxf(m8, __shfl_xor(m8, 2));
      m8 = fmaxf(m8, __shfl_xor(m8, 4));
      m8 = fmaxf(m8, __shfl_xor(m8, 8));
      float s8 = 0.f;
#pragma unroll
      for (int nf = 0; nf < 8; ++nf) {
        float pv = __expf((sc[mf][nf][r] - m8) * SCL);
        sc[mf][nf][r] = pv;
        s8 += pv;
      }
      s8 += __shfl_xor(s8, 1);
      s8 += __shfl_xor(s8, 2);
      s8 += __shfl_xor(s8, 4);
      s8 += __shfl_xor(s8, 8);
      float inv = 1.0f / s8;
      int i = w * 32 + mf * 16 + lg * 4 + r;
      float* ao = attnOut + (size_t)bh * 16384 + (size_t)i * 128;
#pragma unroll
      for (int nf = 0; nf < 8; ++nf) {
        int j = nf * 16 + l15;
        float pv = sc[mf][nf][r] * inv;
        ao[j] = pv;
        pS[(j >> 2) * 512 + i * 4 + (j & 3)] = f2b(pv);
      }
    }
  }
  __syncthreads();

  f32x4 cacc[2][2];
#pragma unroll
  for (int i = 0; i < 2; ++i)
#pragma unroll
    for (int j = 0; j < 2; ++j) cacc[i][j] = (f32x4){0.f, 0.f, 0.f, 0.f};

#pragma unroll
  for (int ks2 = 0; ks2 < 4; ++ks2) {
    const int kqP = ks2 * 8 + lg * 2;
    bf16x8 ap[2];
#pragma unroll
    for (int mf = 0; mf < 2; ++mf) {
      int i = w * 32 + mf * 16 + l15;
      u16x4 lo = *(const u16x4*)(pS + kqP * 512 + i * 4);
      u16x4 hi = *(const u16x4*)(pS + (kqP + 1) * 512 + i * 4);
      ap[mf] = mk8(lo, hi);
    }
#pragma unroll
    for (int nf = 0; nf < 2; ++nf) {
      int d = nf * 16 + l15;
      u16x4 lo = *(const u16x4*)(vS + kqP * 128 + d * 4);
      u16x4 hi = *(const u16x4*)(vS + (kqP + 1) * 128 + d * 4);
      bf16x8 bv8 = mk8(lo, hi);
#pragma unroll
      for (int mf = 0; mf < 2; ++mf)
        cacc[mf][nf] = __builtin_amdgcn_mfma_f32_16x16x32_bf16(ap[mf], bv8, cacc[mf][nf], 0, 0, 0);
    }
  }

  __syncthreads();
#pragma unroll
  for (int mf = 0; mf < 2; ++mf) {
#pragma unroll
    for (int r = 0; r < 4; ++r) {
      int s = w * 32 + mf * 16 + lg * 4 + r;
      int p = s >> 4, q = s & 15;
#pragma unroll
      for (int nf = 0; nf < 2; ++nf) {
        int d = nf * 16 + l15;
        pS[p * 512 + q * 32 + d] = f2b(cacc[mf][nf][r]);
      }
    }
  }
#pragma unroll
  for (int pp = 0; pp < 2; ++pp) {
    int p = w * 2 + pp;
    u16x8 v = *(const u16x8*)&pS[p * 512 + lane * 8];
    *(u16x8*)(ctx + ((size_t)b * 128 + h * 8 + p) * 512 + lane * 8) = v;
  }
}

// ---------------------------------------------------------------------------
// Stage 3-pre: pack Wo [512,512]f32 -> Wot bf16 k-blocked [kq(128)][n(512)][4].
// ---------------------------------------------------------------------------
__global__ __launch_bounds__(256) void wo_prep(
    const float* __restrict__ Wo, u16* __restrict__ Wot)
{
  int idx = blockIdx.x * 256 + threadIdx.x;   // 0..65535
  int k = idx >> 7;
  int n = (idx & 127) * 4;
  f32x4 v = *(const f32x4*)(Wo + k * 512 + n);
  int kq = k >> 2, j = k & 3;
#pragma unroll
  for (int i = 0; i < 4; ++i)
    Wot[kq * 2048 + (n + i) * 4 + j] = f2b(v[i]);
}

// ---------------------------------------------------------------------------
// Stage 3: FUSED out_proj + residual + LayerNorm (UNCHANGED).
// ---------------------------------------------------------------------------
__global__ __launch_bounds__(256) void fused_out_ln(
    const u16* __restrict__ ctx, const u16* __restrict__ Wot,
    const float* __restrict__ bo, const float* __restrict__ query,
    const float* __restrict__ gamma, const float* __restrict__ beta,
    float* __restrict__ out0)
{
  const int bid = blockIdx.x;
  const int m0 = bid * 32;
  const int b = bid >> 2;
  const int t = threadIdx.x, lane = t & 63, wv = t >> 6;
  const int l15 = lane & 15, lg = lane >> 4;
  const int qb = wv * 128;

  __shared__ u16 Bs2[8 * 512 * 4];
  __shared__ float redS[128], redQ[128];

  f32x4 acc[2][8];
#pragma unroll
  for (int i = 0; i < 2; ++i)
#pragma unroll
    for (int j = 0; j < 8; ++j) acc[i][j] = (f32x4){0.f, 0.f, 0.f, 0.f};

  for (int it = 0; it < 16; ++it) {
#pragma unroll
    for (int p = 0; p < 8; ++p) {
      int q = wv * 8 + p;
      const u16* gp = Wot + it * 16384 + q * 512 + lane * 8;
      u16* lp = Bs2 + q * 512;
      __builtin_amdgcn_global_load_lds(
          (const __attribute__((address_space(1))) u32*)gp,
          (__attribute__((address_space(3))) u32*)lp, 16, 0, 0);
    }
    bf16x8 af[2];
#pragma unroll
    for (int mf = 0; mf < 2; ++mf)
      af[mf] = *(const bf16x8*)(ctx + (size_t)(m0 + mf * 16 + l15) * 512 + it * 32 + lg * 8);
    __syncthreads();
#pragma unroll
    for (int nf = 0; nf < 8; ++nf) {
      int n = qb + nf * 16 + l15;
      u16x4 lo = *(const u16x4*)(Bs2 + (2 * lg) * 2048 + n * 4);
      u16x4 hi = *(const u16x4*)(Bs2 + (2 * lg + 1) * 2048 + n * 4);
      bf16x8 bfr = mk8(lo, hi);
      acc[0][nf] = __builtin_amdgcn_mfma_f32_16x16x32_bf16(af[0], bfr, acc[0][nf], 0, 0, 0);
      acc[1][nf] = __builtin_amdgcn_mfma_f32_16x16x32_bf16(af[1], bfr, acc[1][nf], 0, 0, 0);
    }
    __syncthreads();
  }

  float bo8[8], qr8[8], g8[8], be8[8];
#pragma unroll
  for (int nf = 0; nf < 8; ++nf) {
    int col = qb + nf * 16 + l15;
    bo8[nf] = bo[col];
    qr8[nf] = query[b * 512 + col];
    g8[nf] = gamma[col];
    be8[nf] = beta[col];
  }
#pragma unroll
  for (int mf = 0; mf < 2; ++mf)
#pragma unroll
    for (int nf = 0; nf < 8; ++nf)
#pragma unroll
      for (int r = 0; r < 4; ++r)
        acc[mf][nf][r] += bo8[nf] + qr8[nf];

#pragma unroll
  for (int mf = 0; mf < 2; ++mf)
#pragma unroll
    for (int r = 0; r < 4; ++r) {
      float s = 0.f, q2 = 0.f;
#pragma unroll
      for (int nf = 0; nf < 8; ++nf) {
        float x = acc[mf][nf][r];
        s += x; q2 += x * x;
      }
      s += __shfl_xor(s, 1);  s += __shfl_xor(s, 2);
      s += __shfl_xor(s, 4);  s += __shfl_xor(s, 8);
      q2 += __shfl_xor(q2, 1); q2 += __shfl_xor(q2, 2);
      q2 += __shfl_xor(q2, 4); q2 += __shfl_xor(q2, 8);
      int row = mf * 16 + lg * 4 + r;
      if (l15 == 0) { redS[wv * 32 + row] = s; redQ[wv * 32 + row] = q2; }
    }
  __syncthreads();
#pragma unroll
  for (int mf = 0; mf < 2; ++mf)
#pragma unroll
    for (int r = 0; r < 4; ++r) {
      int row = mf * 16 + lg * 4 + r;
      float s = redS[row] + redS[32 + row] + redS[64 + row] + redS[96 + row];
      float q2 = redQ[row] + redQ[32 + row] + redQ[64 + row] + redQ[96 + row];
      float mean = s * (1.f / 512.f);
      float var = q2 * (1.f / 512.f) - mean * mean;
      float rs = rsqrtf(var + 1e-5f);
#pragma unroll
      for (int nf = 0; nf < 8; ++nf)
        out0[(size_t)(m0 + row) * 512 + qb + nf * 16 + l15] =
            (acc[mf][nf][r] - mean) * rs * g8[nf] + be8[nf];
    }
}

// ---------------------------------------------------------------------------
extern "C" void kernel_launch(void* const* d_in, const int* in_sizes, int n_in,
                              void* d_out, int out_size, void* d_ws, size_t ws_size,
                              hipStream_t stream) {
  (void)in_sizes; (void)n_in; (void)out_size; (void)ws_size;
  const float* key   = (const float*)d_in[0];
  const float* value = (const float*)d_in[1];
  const float* query = (const float*)d_in[2];
  const float* Wk    = (const float*)d_in[3];
  const float* bk    = (const float*)d_in[4];
  const float* Wv    = (const float*)d_in[5];
  const float* bv    = (const float*)d_in[6];
  const float* Wq    = (const float*)d_in[7];
  const float* bq    = (const float*)d_in[8];
  const float* Wo    = (const float*)d_in[9];
  const float* bo    = (const float*)d_in[10];
  const float* gamma = (const float*)d_in[11];
  const float* beta  = (const float*)d_in[12];

  char* ws = (char*)d_ws;
  u16* Kp  = (u16*)(ws + 0);               // 16 MB  (dead after attn)
  u16* Vp  = (u16*)(ws + 16777216);        // 16 MB  (dead after attn)
  u16* Qp  = (u16*)(ws + 33554432);        // 16 MB  (dead after attn)
  u16* ctx = (u16*)(ws + 50331648);        // 16 MB  (16384 x 512 bf16)
  u16* Xb  = (u16*)(ws + 50331648);        // 384 KB, overlays ctx (dead before attn)
  u16* Wot = (u16*)(ws + 0);               // 512 KB, overlays dead Kp (post-attn)

  float* out0    = (float*)d_out;          // [128,128,512] LN result
  float* attnOut = out0 + 8388608;         // [2048,128,128] attn

  prep_x<<<dim3(192), 256, 0, stream>>>(key, value, query, Xb);
  qkv_gemm<<<dim3(1536), 256, 0, stream>>>(Xb, Wk, bk, Wv, bv, Wq, bq, Kp, Vp, Qp);
  attn_kernel<<<dim3(2048), 256, 0, stream>>>(Qp, Kp, Vp, attnOut, ctx);
  wo_prep<<<dim3(256), 256, 0, stream>>>(Wo, Wot);
  fused_out_ln<<<dim3(512), 256, 0, stream>>>(ctx, Wot, bo, query, gamma, beta, out0);
}

// Round 9
// 185.285 us; speedup vs baseline: 1.9366x; 1.9366x over previous
//
#include <hip/hip_runtime.h>

typedef unsigned short u16;
typedef unsigned int u32;
typedef __attribute__((ext_vector_type(4))) float f32x4;
typedef __attribute__((ext_vector_type(4))) u16 u16x4;
typedef __attribute__((ext_vector_type(8))) u16 u16x8;
typedef __attribute__((ext_vector_type(8))) __bf16 bf16x8;

#define DEV static __device__ __forceinline__

DEV u16 f2b(float f) {
  u32 u = __builtin_bit_cast(u32, f);
  u32 r = (u + 0x7fffu + ((u >> 16) & 1u)) >> 16;
  return (u16)r;
}

DEV bf16x8 mk8(u16x4 lo, u16x4 hi) {
  u16x8 v = __builtin_shufflevector(lo, hi, 0, 1, 2, 3, 4, 5, 6, 7);
  return __builtin_bit_cast(bf16x8, v);
}

// ---------------------------------------------------------------------------
// Stage 0: convert X (key/value/query, each [128,512] f32) -> bf16 row-major.
// ---------------------------------------------------------------------------
__global__ __launch_bounds__(256) void prep_x(
    const float* __restrict__ key, const float* __restrict__ value,
    const float* __restrict__ query, u16* __restrict__ Xb)
{
  int idx = blockIdx.x * 256 + threadIdx.x;      // 0..49151
  int mat = idx >> 14;
  int off = (idx & 16383) * 4;
  const float* src = mat == 0 ? key : (mat == 1 ? value : query);
  f32x4 v = *(const f32x4*)(src + off);
  u16x4 o;
#pragma unroll
  for (int i = 0; i < 4; ++i) o[i] = __builtin_bit_cast(u16, (__bf16)v[i]);
  *(u16x4*)(Xb + mat * 65536 + off) = o;
}

// ---------------------------------------------------------------------------
// Stage 1: QKV projection.  Xb[mat][128,512]bf16 @ W[512,65536]f32 + b -> bf16.
// grid 1536, block 256 (4 waves, 2x2, 64x64 out each).  BM=128, BN=128, BK=32.
// B reg-staged f32 -> converted -> bf16 LDS (8 KB dbuf); A via LDS-DMA.
// Total LDS 32 KB.  __launch_bounds__(256,4): VGPR budget 128 (no acc spill —
// R8's (256,5) forced 48 VGPRs and spilled acc to scratch: +850 MB HBM).
// LDS permits 5 blocks/CU; VGPR ~100 permits 5; runtime occupancy ~4-5.
// ---------------------------------------------------------------------------
__global__ __launch_bounds__(256, 4) void qkv_gemm(
    const u16* __restrict__ Xb,
    const float* __restrict__ Wk, const float* __restrict__ bk,
    const float* __restrict__ Wv, const float* __restrict__ bv,
    const float* __restrict__ Wq, const float* __restrict__ bq,
    u16* __restrict__ Kp, u16* __restrict__ Vp, u16* __restrict__ Qp)
{
  const int bx = blockIdx.x;
  const int mat = bx >> 9;
  const float* W    = mat == 0 ? Wk : (mat == 1 ? Wv : Wq);
  const float* bias = mat == 0 ? bk : (mat == 1 ? bv : bq);
  u16* out          = mat == 0 ? Kp : (mat == 1 ? Vp : Qp);
  const u16* Xm = Xb + mat * 65536;
  const int n0 = (bx & 511) * 128;

  __shared__ u16 smem[16384];                // 32 KB total

  const int t0 = threadIdx.x, lane = t0 & 63, wv = t0 >> 6;
  const int wm = wv >> 1, wn = wv & 1;
  const int l15 = lane & 15, lg = lane >> 4;

  const int brow = wv * 8 + (lane >> 5);     // +2p: B row this lane stages
  const int bcol = (lane & 31) * 4;          // B col this lane stages

  f32x4 acc[4][4];
#pragma unroll
  for (int i = 0; i < 4; ++i)
#pragma unroll
    for (int j = 0; j < 4; ++j) acc[i][j] = (f32x4){0.f, 0.f, 0.f, 0.f};

  // ---- prologue: stage tile 0 into buffer 0 ----
  {
    f32x4 rB[4];
#pragma unroll
    for (int p = 0; p < 4; ++p) {
      int row = brow + p * 2;
      rB[p] = *(const f32x4*)(W + (size_t)row * 65536 + n0 + bcol);
    }
#pragma unroll
    for (int p = 0; p < 2; ++p) {
      int q = wv * 2 + p;
      int m = q * 16 + (lane >> 2);
      int sc = ((lane & 3) - ((m >> 1) & 3)) & 3;
      const u16* gp = Xm + m * 512 + sc * 8;
      u16* lp = smem + 8192 + q * 512;
      __builtin_amdgcn_global_load_lds(
          (const __attribute__((address_space(1))) u32*)gp,
          (__attribute__((address_space(3))) u32*)lp, 16, 0, 0);
    }
#pragma unroll
    for (int p = 0; p < 4; ++p) {
      int row = brow + p * 2;
      int pc = (bcol + ((row >> 3) << 4)) & 127;
      u16x4 cv;
#pragma unroll
      for (int i = 0; i < 4; ++i) cv[i] = __builtin_bit_cast(u16, (__bf16)rB[p][i]);
      *(u16x4*)&smem[row * 128 + pc] = cv;
    }
    __syncthreads();
  }

  for (int t = 0; t < 16; ++t) {
    const int cur = (t & 1) * 4096, nxt = cur ^ 4096;
    f32x4 rB[4];
    // region 1: issue next-tile loads (covered by compute below)
    if (t < 15) {
      const int k0n = (t + 1) * 32;
#pragma unroll
      for (int p = 0; p < 4; ++p) {
        int row = brow + p * 2;
        rB[p] = *(const f32x4*)(W + (size_t)(k0n + row) * 65536 + n0 + bcol);
      }
#pragma unroll
      for (int p = 0; p < 2; ++p) {
        int q = wv * 2 + p;
        int m = q * 16 + (lane >> 2);
        int sc = ((lane & 3) - ((m >> 1) & 3)) & 3;
        const u16* gp = Xm + m * 512 + k0n + sc * 8;
        u16* lp = smem + 8192 + nxt + q * 512;
        __builtin_amdgcn_global_load_lds(
            (const __attribute__((address_space(1))) u32*)gp,
            (__attribute__((address_space(3))) u32*)lp, 16, 0, 0);
      }
    }
    __builtin_amdgcn_sched_barrier(0);
    // region 2: compute tile t
    {
      bf16x8 af[4];
#pragma unroll
      for (int mf = 0; mf < 4; ++mf) {
        int m = wm * 64 + mf * 16 + l15;
        af[mf] = *(const bf16x8*)&smem[8192 + cur + m * 32 + ((lg + ((m >> 1) & 3)) & 3) * 8];
      }
#pragma unroll
      for (int nf = 0; nf < 4; ++nf) {
        int pc = (wn * 64 + nf * 16 + l15 + lg * 16) & 127;
        u16x8 bw;
#pragma unroll
        for (int j = 0; j < 8; ++j) bw[j] = smem[cur + (lg * 8 + j) * 128 + pc];
        bf16x8 bv = __builtin_bit_cast(bf16x8, bw);
#pragma unroll
        for (int mf = 0; mf < 4; ++mf)
          acc[mf][nf] = __builtin_amdgcn_mfma_f32_16x16x32_bf16(af[mf], bv, acc[mf][nf], 0, 0, 0);
      }
    }
    __builtin_amdgcn_sched_barrier(0);
    // region 3: convert + commit staged B to the other buffer
    if (t < 15) {
#pragma unroll
      for (int p = 0; p < 4; ++p) {
        int row = brow + p * 2;
        int pc = (bcol + ((row >> 3) << 4)) & 127;
        u16x4 cv;
#pragma unroll
        for (int i = 0; i < 4; ++i) cv[i] = __builtin_bit_cast(u16, (__bf16)rB[p][i]);
        *(u16x4*)&smem[nxt + row * 128 + pc] = cv;
      }
    }
    __syncthreads();
  }

  // ---- epilogue: acc + bias -> LDS bf16 tile -> coalesced stores ----
#pragma unroll
  for (int nf = 0; nf < 4; ++nf) {
    int col = wn * 64 + nf * 16 + l15;
    float bv_ = bias[n0 + col];
#pragma unroll
    for (int mf = 0; mf < 4; ++mf) {
      int row0 = wm * 64 + mf * 16 + lg * 4;
#pragma unroll
      for (int r = 0; r < 4; ++r)
        smem[(row0 + r) * 128 + col] = f2b(acc[mf][nf][r] + bv_);
    }
  }
  __syncthreads();
#pragma unroll
  for (int rr = 0; rr < 16; ++rr) {
    int row = wv * 32 + rr * 2 + (lane >> 5);
    int c = (lane & 31) * 4;
    u16x4 v = *(const u16x4*)&smem[row * 128 + c];
    *(u16x4*)(out + (size_t)row * 65536 + n0 + c) = v;
  }
}

// ---------------------------------------------------------------------------
// Stage 2: attention per (b,h) (UNCHANGED).
// ---------------------------------------------------------------------------
__global__ __launch_bounds__(256) void attn_kernel(
    const u16* __restrict__ Qp, const u16* __restrict__ Kp, const u16* __restrict__ Vp,
    float* __restrict__ attnOut, u16* __restrict__ ctx)
{
  const int bh = blockIdx.x;
  const int b = bh >> 4, h = bh & 15;
  const size_t base = (size_t)b * 65536 + h * 4096;

  __shared__ u16 qS[8 * 512];
  __shared__ u16 kS[8 * 512];
  __shared__ u16 vS[32 * 128];
  __shared__ u16 pS[32 * 512];

  const int t = threadIdx.x;
  const int lane = t & 63, w = t >> 6;
  const int l15 = lane & 15, lg = lane >> 4;

#pragma unroll
  for (int p = 0; p < 2; ++p) {
    int idx = p * 256 + t;
    int s = idx >> 2, dc = idx & 3;
    u16x8 qv = *(const u16x8*)(Qp + base + s * 32 + dc * 8);
    u16x8 kv = *(const u16x8*)(Kp + base + s * 32 + dc * 8);
    u16x8 vv = *(const u16x8*)(Vp + base + s * 32 + dc * 8);
    *(u16x4*)(qS + (dc * 2) * 512 + s * 4)     = __builtin_shufflevector(qv, qv, 0, 1, 2, 3);
    *(u16x4*)(qS + (dc * 2 + 1) * 512 + s * 4) = __builtin_shufflevector(qv, qv, 4, 5, 6, 7);
    *(u16x4*)(kS + (dc * 2) * 512 + s * 4)     = __builtin_shufflevector(kv, kv, 0, 1, 2, 3);
    *(u16x4*)(kS + (dc * 2 + 1) * 512 + s * 4) = __builtin_shufflevector(kv, kv, 4, 5, 6, 7);
#pragma unroll
    for (int i = 0; i < 8; ++i)
      vS[(s >> 2) * 128 + (dc * 8 + i) * 4 + (s & 3)] = vv[i];
  }
  __syncthreads();

  f32x4 sc[2][8];
#pragma unroll
  for (int i = 0; i < 2; ++i)
#pragma unroll
    for (int j = 0; j < 8; ++j) sc[i][j] = (f32x4){0.f, 0.f, 0.f, 0.f};

  {
    const int kqA = lg * 2;
    bf16x8 aq[2];
#pragma unroll
    for (int mf = 0; mf < 2; ++mf) {
      int m = w * 32 + mf * 16 + l15;
      u16x4 lo = *(const u16x4*)(qS + kqA * 512 + m * 4);
      u16x4 hi = *(const u16x4*)(qS + (kqA + 1) * 512 + m * 4);
      aq[mf] = mk8(lo, hi);
    }
#pragma unroll
    for (int nf = 0; nf < 8; ++nf) {
      int j = nf * 16 + l15;
      u16x4 lo = *(const u16x4*)(kS + kqA * 512 + j * 4);
      u16x4 hi = *(const u16x4*)(kS + (kqA + 1) * 512 + j * 4);
      bf16x8 bk8 = mk8(lo, hi);
#pragma unroll
      for (int mf = 0; mf < 2; ++mf)
        sc[mf][nf] = __builtin_amdgcn_mfma_f32_16x16x32_bf16(aq[mf], bk8, sc[mf][nf], 0, 0, 0);
    }
  }

  const float SCL = 0.70710678118654752f;
#pragma unroll
  for (int mf = 0; mf < 2; ++mf) {
#pragma unroll
    for (int r = 0; r < 4; ++r) {
      float m8 = -1e30f;
#pragma unroll
      for (int nf = 0; nf < 8; ++nf) m8 = fmaxf(m8, sc[mf][nf][r]);
      m8 = fmaxf(m8, __shfl_xor(m8, 1));
      m8 = fmaxf(m8, __shfl_xor(m8, 2));
      m8 = fmaxf(m8, __shfl_xor(m8, 4));
      m8 = fmaxf(m8, __shfl_xor(m8, 8));
      float s8 = 0.f;
#pragma unroll
      for (int nf = 0; nf < 8; ++nf) {
        float pv = __expf((sc[mf][nf][r] - m8) * SCL);
        sc[mf][nf][r] = pv;
        s8 += pv;
      }
      s8 += __shfl_xor(s8, 1);
      s8 += __shfl_xor(s8, 2);
      s8 += __shfl_xor(s8, 4);
      s8 += __shfl_xor(s8, 8);
      float inv = 1.0f / s8;
      int i = w * 32 + mf * 16 + lg * 4 + r;
      float* ao = attnOut + (size_t)bh * 16384 + (size_t)i * 128;
#pragma unroll
      for (int nf = 0; nf < 8; ++nf) {
        int j = nf * 16 + l15;
        float pv = sc[mf][nf][r] * inv;
        ao[j] = pv;
        pS[(j >> 2) * 512 + i * 4 + (j & 3)] = f2b(pv);
      }
    }
  }
  __syncthreads();

  f32x4 cacc[2][2];
#pragma unroll
  for (int i = 0; i < 2; ++i)
#pragma unroll
    for (int j = 0; j < 2; ++j) cacc[i][j] = (f32x4){0.f, 0.f, 0.f, 0.f};

#pragma unroll
  for (int ks2 = 0; ks2 < 4; ++ks2) {
    const int kqP = ks2 * 8 + lg * 2;
    bf16x8 ap[2];
#pragma unroll
    for (int mf = 0; mf < 2; ++mf) {
      int i = w * 32 + mf * 16 + l15;
      u16x4 lo = *(const u16x4*)(pS + kqP * 512 + i * 4);
      u16x4 hi = *(const u16x4*)(pS + (kqP + 1) * 512 + i * 4);
      ap[mf] = mk8(lo, hi);
    }
#pragma unroll
    for (int nf = 0; nf < 2; ++nf) {
      int d = nf * 16 + l15;
      u16x4 lo = *(const u16x4*)(vS + kqP * 128 + d * 4);
      u16x4 hi = *(const u16x4*)(vS + (kqP + 1) * 128 + d * 4);
      bf16x8 bv8 = mk8(lo, hi);
#pragma unroll
      for (int mf = 0; mf < 2; ++mf)
        cacc[mf][nf] = __builtin_amdgcn_mfma_f32_16x16x32_bf16(ap[mf], bv8, cacc[mf][nf], 0, 0, 0);
    }
  }

  __syncthreads();
#pragma unroll
  for (int mf = 0; mf < 2; ++mf) {
#pragma unroll
    for (int r = 0; r < 4; ++r) {
      int s = w * 32 + mf * 16 + lg * 4 + r;
      int p = s >> 4, q = s & 15;
#pragma unroll
      for (int nf = 0; nf < 2; ++nf) {
        int d = nf * 16 + l15;
        pS[p * 512 + q * 32 + d] = f2b(cacc[mf][nf][r]);
      }
    }
  }
#pragma unroll
  for (int pp = 0; pp < 2; ++pp) {
    int p = w * 2 + pp;
    u16x8 v = *(const u16x8*)&pS[p * 512 + lane * 8];
    *(u16x8*)(ctx + ((size_t)b * 128 + h * 8 + p) * 512 + lane * 8) = v;
  }
}

// ---------------------------------------------------------------------------
// Stage 3-pre: pack Wo [512,512]f32 -> Wot bf16 k-blocked [kq(128)][n(512)][4].
// ---------------------------------------------------------------------------
__global__ __launch_bounds__(256) void wo_prep(
    const float* __restrict__ Wo, u16* __restrict__ Wot)
{
  int idx = blockIdx.x * 256 + threadIdx.x;   // 0..65535
  int k = idx >> 7;
  int n = (idx & 127) * 4;
  f32x4 v = *(const f32x4*)(Wo + k * 512 + n);
  int kq = k >> 2, j = k & 3;
#pragma unroll
  for (int i = 0; i < 4; ++i)
    Wot[kq * 2048 + (n + i) * 4 + j] = f2b(v[i]);
}

// ---------------------------------------------------------------------------
// Stage 3: FUSED out_proj + residual + LayerNorm (UNCHANGED).
// ---------------------------------------------------------------------------
__global__ __launch_bounds__(256) void fused_out_ln(
    const u16* __restrict__ ctx, const u16* __restrict__ Wot,
    const float* __restrict__ bo, const float* __restrict__ query,
    const float* __restrict__ gamma, const float* __restrict__ beta,
    float* __restrict__ out0)
{
  const int bid = blockIdx.x;
  const int m0 = bid * 32;
  const int b = bid >> 2;
  const int t = threadIdx.x, lane = t & 63, wv = t >> 6;
  const int l15 = lane & 15, lg = lane >> 4;
  const int qb = wv * 128;

  __shared__ u16 Bs2[8 * 512 * 4];
  __shared__ float redS[128], redQ[128];

  f32x4 acc[2][8];
#pragma unroll
  for (int i = 0; i < 2; ++i)
#pragma unroll
    for (int j = 0; j < 8; ++j) acc[i][j] = (f32x4){0.f, 0.f, 0.f, 0.f};

  for (int it = 0; it < 16; ++it) {
#pragma unroll
    for (int p = 0; p < 8; ++p) {
      int q = wv * 8 + p;
      const u16* gp = Wot + it * 16384 + q * 512 + lane * 8;
      u16* lp = Bs2 + q * 512;
      __builtin_amdgcn_global_load_lds(
          (const __attribute__((address_space(1))) u32*)gp,
          (__attribute__((address_space(3))) u32*)lp, 16, 0, 0);
    }
    bf16x8 af[2];
#pragma unroll
    for (int mf = 0; mf < 2; ++mf)
      af[mf] = *(const bf16x8*)(ctx + (size_t)(m0 + mf * 16 + l15) * 512 + it * 32 + lg * 8);
    __syncthreads();
#pragma unroll
    for (int nf = 0; nf < 8; ++nf) {
      int n = qb + nf * 16 + l15;
      u16x4 lo = *(const u16x4*)(Bs2 + (2 * lg) * 2048 + n * 4);
      u16x4 hi = *(const u16x4*)(Bs2 + (2 * lg + 1) * 2048 + n * 4);
      bf16x8 bfr = mk8(lo, hi);
      acc[0][nf] = __builtin_amdgcn_mfma_f32_16x16x32_bf16(af[0], bfr, acc[0][nf], 0, 0, 0);
      acc[1][nf] = __builtin_amdgcn_mfma_f32_16x16x32_bf16(af[1], bfr, acc[1][nf], 0, 0, 0);
    }
    __syncthreads();
  }

  float bo8[8], qr8[8], g8[8], be8[8];
#pragma unroll
  for (int nf = 0; nf < 8; ++nf) {
    int col = qb + nf * 16 + l15;
    bo8[nf] = bo[col];
    qr8[nf] = query[b * 512 + col];
    g8[nf] = gamma[col];
    be8[nf] = beta[col];
  }
#pragma unroll
  for (int mf = 0; mf < 2; ++mf)
#pragma unroll
    for (int nf = 0; nf < 8; ++nf)
#pragma unroll
      for (int r = 0; r < 4; ++r)
        acc[mf][nf][r] += bo8[nf] + qr8[nf];

#pragma unroll
  for (int mf = 0; mf < 2; ++mf)
#pragma unroll
    for (int r = 0; r < 4; ++r) {
      float s = 0.f, q2 = 0.f;
#pragma unroll
      for (int nf = 0; nf < 8; ++nf) {
        float x = acc[mf][nf][r];
        s += x; q2 += x * x;
      }
      s += __shfl_xor(s, 1);  s += __shfl_xor(s, 2);
      s += __shfl_xor(s, 4);  s += __shfl_xor(s, 8);
      q2 += __shfl_xor(q2, 1); q2 += __shfl_xor(q2, 2);
      q2 += __shfl_xor(q2, 4); q2 += __shfl_xor(q2, 8);
      int row = mf * 16 + lg * 4 + r;
      if (l15 == 0) { redS[wv * 32 + row] = s; redQ[wv * 32 + row] = q2; }
    }
  __syncthreads();
#pragma unroll
  for (int mf = 0; mf < 2; ++mf)
#pragma unroll
    for (int r = 0; r < 4; ++r) {
      int row = mf * 16 + lg * 4 + r;
      float s = redS[row] + redS[32 + row] + redS[64 + row] + redS[96 + row];
      float q2 = redQ[row] + redQ[32 + row] + redQ[64 + row] + redQ[96 + row];
      float mean = s * (1.f / 512.f);
      float var = q2 * (1.f / 512.f) - mean * mean;
      float rs = rsqrtf(var + 1e-5f);
#pragma unroll
      for (int nf = 0; nf < 8; ++nf)
        out0[(size_t)(m0 + row) * 512 + qb + nf * 16 + l15] =
            (acc[mf][nf][r] - mean) * rs * g8[nf] + be8[nf];
    }
}

// ---------------------------------------------------------------------------
extern "C" void kernel_launch(void* const* d_in, const int* in_sizes, int n_in,
                              void* d_out, int out_size, void* d_ws, size_t ws_size,
                              hipStream_t stream) {
  (void)in_sizes; (void)n_in; (void)out_size; (void)ws_size;
  const float* key   = (const float*)d_in[0];
  const float* value = (const float*)d_in[1];
  const float* query = (const float*)d_in[2];
  const float* Wk    = (const float*)d_in[3];
  const float* bk    = (const float*)d_in[4];
  const float* Wv    = (const float*)d_in[5];
  const float* bv    = (const float*)d_in[6];
  const float* Wq    = (const float*)d_in[7];
  const float* bq    = (const float*)d_in[8];
  const float* Wo    = (const float*)d_in[9];
  const float* bo    = (const float*)d_in[10];
  const float* gamma = (const float*)d_in[11];
  const float* beta  = (const float*)d_in[12];

  char* ws = (char*)d_ws;
  u16* Kp  = (u16*)(ws + 0);               // 16 MB  (dead after attn)
  u16* Vp  = (u16*)(ws + 16777216);        // 16 MB  (dead after attn)
  u16* Qp  = (u16*)(ws + 33554432);        // 16 MB  (dead after attn)
  u16* ctx = (u16*)(ws + 50331648);        // 16 MB  (16384 x 512 bf16)
  u16* Xb  = (u16*)(ws + 50331648);        // 384 KB, overlays ctx (dead before attn)
  u16* Wot = (u16*)(ws + 0);               // 512 KB, overlays dead Kp (post-attn)

  float* out0    = (float*)d_out;          // [128,128,512] LN result
  float* attnOut = out0 + 8388608;         // [2048,128,128] attn

  prep_x<<<dim3(192), 256, 0, stream>>>(key, value, query, Xb);
  qkv_gemm<<<dim3(1536), 256, 0, stream>>>(Xb, Wk, bk, Wv, bv, Wq, bq, Kp, Vp, Qp);
  attn_kernel<<<dim3(2048), 256, 0, stream>>>(Qp, Kp, Vp, attnOut, ctx);
  wo_prep<<<dim3(256), 256, 0, stream>>>(Wo, Wot);
  fused_out_ln<<<dim3(512), 256, 0, stream>>>(ctx, Wot, bo, query, gamma, beta, out0);
}